// Round 13
// baseline (179.040 us; speedup 1.0000x reference)
//
#include <hip/hip_runtime.h>
#include <hip/hip_bf16.h>
#include <hip/hip_fp16.h>

static constexpr int KDIM = 96;
static constexpr int BSH = 7;              // 128 nodes per bucket
static constexpr int BNODES = 1 << BSH;
static constexpr int MAXBK = 400;          // >= ceil(50000/128)=391
static constexpr int CAP = 4096;           // fixed bucket capacity (mean 2046, sigma 45)

typedef _Float16 f16x8 __attribute__((ext_vector_type(8)));
typedef float f32x4 __attribute__((ext_vector_type(4)));

// ---- GEMM96 body (f32 A, fp16 out), W transposed in LDS --------------------
__device__ __forceinline__ void gemm96_f32_body(const float* __restrict__ x,
                                                const float* __restrict__ Wg,
                                                __half* __restrict__ out, int N,
                                                int gb, char* sm) {
  _Float16* Wt = (_Float16*)sm;            // [96][104]
  const int tid = threadIdx.x;
  for (int i = tid; i < 96 * 96; i += 256) {
    int k = i / 96, j = i - k * 96;
    Wt[j * 104 + k] = (_Float16)Wg[i];
  }
  __syncthreads();
  const int wave = tid >> 6;
  const int l = tid & 63;
  const int crow = l & 15;
  const int kgrp = l >> 4;
  int r = gb * 64 + wave * 16 + crow;
  int rc = (r < N) ? r : (N - 1);
  f16x8 a[3];
  const float* ap = x + (size_t)rc * 96 + kgrp * 8;
#pragma unroll
  for (int ks = 0; ks < 3; ++ks) {
    float4 u = *(const float4*)(ap + ks * 32);
    float4 w = *(const float4*)(ap + ks * 32 + 4);
    a[ks][0] = (_Float16)u.x; a[ks][1] = (_Float16)u.y;
    a[ks][2] = (_Float16)u.z; a[ks][3] = (_Float16)u.w;
    a[ks][4] = (_Float16)w.x; a[ks][5] = (_Float16)w.y;
    a[ks][6] = (_Float16)w.z; a[ks][7] = (_Float16)w.w;
  }
  const int rbase = gb * 64 + wave * 16 + kgrp * 4;
#pragma unroll
  for (int nt = 0; nt < 6; ++nt) {
    f32x4 c = {0.f, 0.f, 0.f, 0.f};
#pragma unroll
    for (int ks = 0; ks < 3; ++ks) {
      f16x8 b = *(const f16x8*)&Wt[(nt * 16 + crow) * 104 + ks * 32 + kgrp * 8];
      c = __builtin_amdgcn_mfma_f32_16x16x32_f16(a[ks], b, c, 0, 0, 0);
    }
#pragma unroll
    for (int reg = 0; reg < 4; ++reg) {
      int R = rbase + reg;
      if (R < N) out[(size_t)R * 96 + nt * 16 + crow] = (__half)c[reg];
    }
  }
}

// ---- fat kernel 1: scatter (blocks<NCH) + GEMM1 + W-transpose --------------
// Scatter: per-chunk LDS bucket hist -> one global reservation per
// (chunk,bucket) into fixed-capacity regions tmp[b*CAP..]; plus one global
// atomicAdd(cnt[dst]) per edge for per-node degrees (L2-resident table).
__global__ __launch_bounds__(256) void ksca_gemm1(
    const int* __restrict__ src, const int* __restrict__ dst,
    int* __restrict__ cnt, int* __restrict__ bcur, unsigned* __restrict__ tmp,
    int E, int NBK, int chunk,
    const float* __restrict__ x, const float* __restrict__ W1,
    __half* __restrict__ tA, int N,
    const float* __restrict__ W2, const float* __restrict__ W3,
    _Float16* __restrict__ Wt2, _Float16* __restrict__ Wt3,
    int NCH, int gG) {
  __shared__ __align__(16) char sm[96 * 104 * 2];
  if (blockIdx.x < (unsigned)NCH) {
    int* h = (int*)sm;
    int* base = h + MAXBK;
    int lo = blockIdx.x * chunk;
    int hi = min(lo + chunk, E);
    for (int i = threadIdx.x; i < NBK; i += 256) h[i] = 0;
    __syncthreads();
    for (int e = lo + threadIdx.x; e < hi; e += 256) {
      int d = dst[e];
      atomicAdd(&h[d >> BSH], 1);
      atomicAdd(&cnt[d], 1);
    }
    __syncthreads();
    for (int i = threadIdx.x; i < NBK; i += 256) {
      int c = h[i];
      base[i] = c ? (i * CAP + atomicAdd(&bcur[i], c)) : 0;
      h[i] = 0;
    }
    __syncthreads();
    for (int e = lo + threadIdx.x; e < hi; e += 256) {
      int d = dst[e];
      int b = d >> BSH;
      int p = base[b] + atomicAdd(&h[b], 1);
      tmp[p] = (unsigned)src[e] | ((unsigned)(d & (BNODES - 1)) << 16);
    }
  } else if (blockIdx.x < (unsigned)(NCH + gG)) {
    gemm96_f32_body(x, W1, tA, N, blockIdx.x - NCH, sm);
  } else {
    for (int i = threadIdx.x; i < 96 * 96; i += 256) {
      int k = i / 96, j = i - k * 96;
      Wt2[j * 96 + k] = (_Float16)W2[i];
    }
    for (int i = threadIdx.x; i < 96 * 32; i += 256) {
      int k = i / 32, j = i - k * 32;
      Wt3[j * 96 + k] = (_Float16)W3[i];
    }
  }
}

// ---- kernel 2: rs ranges (pad-4 LDS scan + global cursor) + dinv ------------
__global__ __launch_bounds__(256) void k_rs(const int* __restrict__ cnt,
                                            int* __restrict__ cursor,
                                            float* __restrict__ dinv,
                                            int2* __restrict__ rs, int N) {
  __shared__ int scn[256];
  __shared__ int gbs;
  int t = threadIdx.x;
  int v = blockIdx.x * 256 + t;
  int c = (v < N) ? cnt[v] : 0;
  int p = (c + 3) & ~3;
  scn[t] = p;
  __syncthreads();
  for (int o = 1; o < 256; o <<= 1) {
    int a = (t >= o) ? scn[t - o] : 0;
    __syncthreads();
    scn[t] += a;
    __syncthreads();
  }
  if (t == 0) gbs = atomicAdd(cursor, scn[255]);
  __syncthreads();
  if (v < N) {
    int beg = gbs + scn[t] - p;
    rs[v] = make_int2(beg, beg + p);
    dinv[v] = rsqrtf((float)c + 1.0f);  // +1 self-loop
  }
}

// ---- kernel 3: per-bucket final scatter into padded CSR ---------------------
// ew = {src:16 | fp16(dinv[src])<<16}, rows padded to x4 with 0.
__global__ __launch_bounds__(256) void kb_final3(const unsigned* __restrict__ tmp,
                                                 const int* __restrict__ bcur,
                                                 const int2* __restrict__ rs,
                                                 const float* __restrict__ dinv,
                                                 unsigned* __restrict__ ew, int N) {
  __shared__ int beg[BNODES];
  __shared__ int endp[BNODES];
  __shared__ int lcur[BNODES];
  int b = blockIdx.x;
  int t = threadIdx.x;
  int v0 = b << BSH;
  if (t < BNODES) {
    int v = v0 + t;
    if (v < N) {
      int2 r = rs[v];
      beg[t] = r.x;
      endp[t] = r.y;
    } else {
      beg[t] = 0;
      endp[t] = 0;
    }
    lcur[t] = 0;
  }
  __syncthreads();
  const unsigned* tb = tmp + (size_t)b * CAP;
  int cntb = bcur[b];
  for (int p = t; p < cntb; p += 256) {
    unsigned u = tb[p];
    int dl = (u >> 16) & (BNODES - 1);
    int s = u & 0xFFFF;
    int pos = beg[dl] + atomicAdd(&lcur[dl], 1);
    unsigned hw = (unsigned)__half_as_ushort(__float2half(dinv[s]));
    ew[pos] = (unsigned)s | (hw << 16);
  }
  __syncthreads();
  if (t < BNODES) {
    int p = beg[t] + lcur[t];
    int end = endp[t];
    for (; p < end; ++p) ew[p] = 0u;  // src=0, w=0: contributes nothing
  }
}

// ---- fused: agg96 (bias+relu) -> tiny LDS -> MFMA with pre-transposed W -----
// 16 nodes per block: 4 waves x 4 sequential nodes (keeps TLP at occupancy
// cap). Phase B reads B-fragments from pre-transposed global fp16 Wt (L2);
// LDS = A[16][104] only.
template <int DOUT>
__global__ __launch_bounds__(256) void kfuse(const __half* __restrict__ t,
                                             const int2* __restrict__ rs,
                                             const unsigned* __restrict__ ew,
                                             const float* __restrict__ dinv,
                                             const float* __restrict__ bias,
                                             const _Float16* __restrict__ Wt,
                                             __half* __restrict__ out, int N) {
  __shared__ _Float16 A[16 * 104];
  const int tid = threadIdx.x;
  const int wave = tid >> 6;
  const int lane = tid & 63;
  const int li = (lane < 48) ? lane : 47;
  const int fb = li << 2;
  const char* tb = (const char*)t;
  const float bx = bias[2 * li];
  const float by = bias[2 * li + 1];
#pragma unroll
  for (int i = 0; i < 4; ++i) {
    int row = wave * 4 + i;
    int v = blockIdx.x * 16 + row;
    if (v < N) {
      float dv = dinv[v];
      float2 acc;
      {
        __half2 r = *(const __half2*)(tb + (size_t)v * 192 + fb);
        float2 f = __half22float2(r);
        acc.x = dv * f.x;
        acc.y = dv * f.y;
      }
      int2 range = rs[v];
      int e = range.x;
      const int e1 = range.y;              // padded to x4, 16B aligned
      for (; e < e1; e += 4) {
        uint4 q = *(const uint4*)(ew + e); // 4 edges, wave-uniform broadcast
        __half2 r0 = *(const __half2*)(tb + (size_t)(q.x & 0xFFFF) * 192 + fb);
        __half2 r1 = *(const __half2*)(tb + (size_t)(q.y & 0xFFFF) * 192 + fb);
        __half2 r2 = *(const __half2*)(tb + (size_t)(q.z & 0xFFFF) * 192 + fb);
        __half2 r3 = *(const __half2*)(tb + (size_t)(q.w & 0xFFFF) * 192 + fb);
        float2 a0 = __half22float2(r0), a1 = __half22float2(r1);
        float2 a2 = __half22float2(r2), a3 = __half22float2(r3);
        float w0 = __half2float(__ushort_as_half((unsigned short)(q.x >> 16)));
        float w1 = __half2float(__ushort_as_half((unsigned short)(q.y >> 16)));
        float w2 = __half2float(__ushort_as_half((unsigned short)(q.z >> 16)));
        float w3 = __half2float(__ushort_as_half((unsigned short)(q.w >> 16)));
        acc.x = fmaf(w0, a0.x, acc.x); acc.y = fmaf(w0, a0.y, acc.y);
        acc.x = fmaf(w1, a1.x, acc.x); acc.y = fmaf(w1, a1.y, acc.y);
        acc.x = fmaf(w2, a2.x, acc.x); acc.y = fmaf(w2, a2.y, acc.y);
        acc.x = fmaf(w3, a3.x, acc.x); acc.y = fmaf(w3, a3.y, acc.y);
      }
      if (lane < 48) {
        float rx = fmaxf(fmaf(dv, acc.x, bx), 0.f);
        float ry = fmaxf(fmaf(dv, acc.y, by), 0.f);
        A[row * 104 + 2 * li] = (_Float16)rx;
        A[row * 104 + 2 * li + 1] = (_Float16)ry;
      }
    }
  }
  __syncthreads();
  const int crow = lane & 15;
  const int kgrp = lane >> 4;
  f16x8 a[3];
  const _Float16* arow = &A[crow * 104 + kgrp * 8];
#pragma unroll
  for (int ks = 0; ks < 3; ++ks) a[ks] = *(const f16x8*)(arow + ks * 32);
  const int rbase = blockIdx.x * 16 + kgrp * 4;
#pragma unroll
  for (int w2 = 0; w2 < 2; ++w2) {
    int nt = wave + 4 * w2;
    if (nt >= DOUT / 16) break;
    f32x4 c = {0.f, 0.f, 0.f, 0.f};
#pragma unroll
    for (int ks = 0; ks < 3; ++ks) {
      f16x8 b = *(const f16x8*)&Wt[(nt * 16 + crow) * 96 + ks * 32 + kgrp * 8];
      c = __builtin_amdgcn_mfma_f32_16x16x32_f16(a[ks], b, c, 0, 0, 0);
    }
#pragma unroll
    for (int reg = 0; reg < 4; ++reg) {
      int R = rbase + reg;
      if (R < N) out[(size_t)R * DOUT + nt * 16 + crow] = (__half)c[reg];
    }
  }
}

// D=32 final layer: half-wave per node, f32 out
__global__ __launch_bounds__(256) void k_agg32h(const __half* __restrict__ t,
                                                const int2* __restrict__ rs,
                                                const unsigned* __restrict__ ew,
                                                const float* __restrict__ dinv,
                                                const float* __restrict__ bias,
                                                float* __restrict__ out, int N) {
  int half = threadIdx.x >> 5;
  int lane = threadIdx.x & 31;
  int v = blockIdx.x * 8 + half;
  if (v >= N) return;
  const char* tb = (const char*)t;
  const int fb = lane << 1;
  float dv = dinv[v];
  float acc = dv * __half2float(*(const __half*)(tb + (size_t)v * 64 + fb));
  int2 range = rs[v];
  int e = range.x;
  const int e1 = range.y;
  for (; e < e1; e += 4) {
    uint4 q = *(const uint4*)(ew + e);
    float a0 = __half2float(*(const __half*)(tb + (size_t)(q.x & 0xFFFF) * 64 + fb));
    float a1 = __half2float(*(const __half*)(tb + (size_t)(q.y & 0xFFFF) * 64 + fb));
    float a2 = __half2float(*(const __half*)(tb + (size_t)(q.z & 0xFFFF) * 64 + fb));
    float a3 = __half2float(*(const __half*)(tb + (size_t)(q.w & 0xFFFF) * 64 + fb));
    acc = fmaf(__half2float(__ushort_as_half((unsigned short)(q.x >> 16))), a0, acc);
    acc = fmaf(__half2float(__ushort_as_half((unsigned short)(q.y >> 16))), a1, acc);
    acc = fmaf(__half2float(__ushort_as_half((unsigned short)(q.z >> 16))), a2, acc);
    acc = fmaf(__half2float(__ushort_as_half((unsigned short)(q.w >> 16))), a3, acc);
  }
  out[(size_t)v * 32 + lane] = fmaf(dv, acc, bias[lane]);
}

// ---- launch ----------------------------------------------------------------

extern "C" void kernel_launch(void* const* d_in, const int* in_sizes, int n_in,
                              void* d_out, int out_size, void* d_ws, size_t ws_size,
                              hipStream_t stream) {
  const float* x  = (const float*)d_in[0];
  const int*   ei = (const int*)d_in[1];
  const float* W1 = (const float*)d_in[2];
  const float* b1 = (const float*)d_in[3];
  const float* W2 = (const float*)d_in[4];
  const float* b2 = (const float*)d_in[5];
  const float* W3 = (const float*)d_in[6];
  const float* b3 = (const float*)d_in[7];
  float* out = (float*)d_out;

  const int N = in_sizes[0] / KDIM;
  const int E = in_sizes[1] / 2;
  const int* src = ei;
  const int* dst = ei + E;
  const int NBK = (N + BNODES - 1) >> BSH;

  char* w = (char*)d_ws;
  size_t off = 0;
  auto alloc = [&](size_t bytes) {
    char* p = w + off;
    off = (off + bytes + 255) & ~(size_t)255;
    return p;
  };
  // meta: [bcur MAXBK][cursor+pad 8][cnt N] -- single memset covers all
  int*       meta     = (int*)alloc((size_t)(MAXBK + 8 + N) * 4);
  int*       bcur     = meta;
  int*       cursor   = meta + MAXBK;
  int*       cnt      = meta + MAXBK + 8;
  float*     dinv     = (float*)alloc((size_t)N * 4);
  int2*      rs       = (int2*)alloc((size_t)N * 8);
  unsigned*  tmp      = (unsigned*)alloc((size_t)MAXBK * CAP * 4);
  unsigned*  ew       = (unsigned*)alloc((size_t)(E + 4 * (size_t)N + 16) * 4);
  __half*    tA       = (__half*)alloc((size_t)N * KDIM * 2);
  __half*    tB       = (__half*)alloc((size_t)N * KDIM * 2);
  __half*    tC       = (__half*)alloc((size_t)N * 32 * 2);
  _Float16*  Wt2      = (_Float16*)alloc((size_t)96 * 96 * 2);
  _Float16*  Wt3      = (_Float16*)alloc((size_t)32 * 96 * 2);

  hipMemsetAsync(meta, 0, (size_t)(MAXBK + 8 + N) * 4, stream);

  const int NCH = 512;
  const int chunk = (E + NCH - 1) / NCH;
  const int gG = (N + 63) / 64;
  const int gF = (N + 15) / 16;
  const int gA8 = (N + 7) / 8;

  ksca_gemm1<<<NCH + gG + 1, 256, 0, stream>>>(src, dst, cnt, bcur, tmp, E, NBK,
                                               chunk, x, W1, tA, N, W2, W3, Wt2,
                                               Wt3, NCH, gG);
  k_rs<<<(N + 255) / 256, 256, 0, stream>>>(cnt, cursor, dinv, rs, N);
  kb_final3<<<NBK, 256, 0, stream>>>(tmp, bcur, rs, dinv, ew, N);

  kfuse<96><<<gF, 256, 0, stream>>>(tA, rs, ew, dinv, b1, Wt2, tB, N);
  kfuse<32><<<gF, 256, 0, stream>>>(tB, rs, ew, dinv, b2, Wt3, tC, N);
  k_agg32h<<<gA8, 256, 0, stream>>>(tC, rs, ew, dinv, b3, out, N);
}

// Round 14
// 162.000 us; speedup vs baseline: 1.1052x; 1.1052x over previous
//
#include <hip/hip_runtime.h>
#include <hip/hip_bf16.h>
#include <hip/hip_fp16.h>

static constexpr int KDIM = 96;
static constexpr int BSH = 7;              // 128 nodes per bucket
static constexpr int BNODES = 1 << BSH;
static constexpr int MAXBK = 400;          // >= ceil(50000/128)=391

typedef _Float16 f16x8 __attribute__((ext_vector_type(8)));
typedef float f32x4 __attribute__((ext_vector_type(4)));

// ---- GEMM96 body (f32 A, fp16 out), W transposed in LDS --------------------
__device__ __forceinline__ void gemm96_f32_body(const float* __restrict__ x,
                                                const float* __restrict__ Wg,
                                                __half* __restrict__ out, int N,
                                                int gb, char* sm) {
  _Float16* Wt = (_Float16*)sm;            // [96][104]
  const int tid = threadIdx.x;
  for (int i = tid; i < 96 * 96; i += 256) {
    int k = i / 96, j = i - k * 96;
    Wt[j * 104 + k] = (_Float16)Wg[i];
  }
  __syncthreads();
  const int wave = tid >> 6;
  const int l = tid & 63;
  const int crow = l & 15;
  const int kgrp = l >> 4;
  int r = gb * 64 + wave * 16 + crow;
  int rc = (r < N) ? r : (N - 1);
  f16x8 a[3];
  const float* ap = x + (size_t)rc * 96 + kgrp * 8;
#pragma unroll
  for (int ks = 0; ks < 3; ++ks) {
    float4 u = *(const float4*)(ap + ks * 32);
    float4 w = *(const float4*)(ap + ks * 32 + 4);
    a[ks][0] = (_Float16)u.x; a[ks][1] = (_Float16)u.y;
    a[ks][2] = (_Float16)u.z; a[ks][3] = (_Float16)u.w;
    a[ks][4] = (_Float16)w.x; a[ks][5] = (_Float16)w.y;
    a[ks][6] = (_Float16)w.z; a[ks][7] = (_Float16)w.w;
  }
  const int rbase = gb * 64 + wave * 16 + kgrp * 4;
#pragma unroll
  for (int nt = 0; nt < 6; ++nt) {
    f32x4 c = {0.f, 0.f, 0.f, 0.f};
#pragma unroll
    for (int ks = 0; ks < 3; ++ks) {
      f16x8 b = *(const f16x8*)&Wt[(nt * 16 + crow) * 104 + ks * 32 + kgrp * 8];
      c = __builtin_amdgcn_mfma_f32_16x16x32_f16(a[ks], b, c, 0, 0, 0);
    }
#pragma unroll
    for (int reg = 0; reg < 4; ++reg) {
      int R = rbase + reg;
      if (R < N) out[(size_t)R * 96 + nt * 16 + crow] = (__half)c[reg];
    }
  }
}

// ---- fat kernel: hist (blocks<256) + GEMM1 (next gG) + W-transpose (last) --
__global__ __launch_bounds__(256) void khist_gemm1(const int* __restrict__ dst,
                                                   int* __restrict__ gbcnt,
                                                   int E, int NBK,
                                                   const float* __restrict__ x,
                                                   const float* __restrict__ W1,
                                                   __half* __restrict__ tA, int N,
                                                   const float* __restrict__ W2,
                                                   const float* __restrict__ W3,
                                                   _Float16* __restrict__ Wt2,
                                                   _Float16* __restrict__ Wt3,
                                                   int gG) {
  __shared__ __align__(16) char sm[96 * 104 * 2];
  if (blockIdx.x < 256) {
    int* h = (int*)sm;
    for (int i = threadIdx.x; i < NBK; i += 256) h[i] = 0;
    __syncthreads();
    for (int e = blockIdx.x * 256 + threadIdx.x; e < E; e += 256 * 256)
      atomicAdd(&h[dst[e] >> BSH], 1);
    __syncthreads();
    for (int i = threadIdx.x; i < NBK; i += 256)
      if (h[i]) atomicAdd(&gbcnt[i], h[i]);
  } else if (blockIdx.x < 256 + gG) {
    gemm96_f32_body(x, W1, tA, N, blockIdx.x - 256, sm);
  } else {
    for (int i = threadIdx.x; i < 96 * 96; i += 256) {
      int k = i / 96, j = i - k * 96;
      Wt2[j * 96 + k] = (_Float16)W2[i];
    }
    for (int i = threadIdx.x; i < 96 * 32; i += 256) {
      int k = i / 32, j = i - k * 32;
      Wt3[j * 96 + k] = (_Float16)W3[i];
    }
  }
}

__global__ void kb_scanb(const int* __restrict__ gbcnt, int* __restrict__ bstart,
                         int* __restrict__ bcur, int NBK,
                         __half* __restrict__ dinv16, int N) {
  __shared__ int s[512];
  int t = threadIdx.x;
  int v = (t < NBK) ? gbcnt[t] : 0;
  s[t] = v;
  __syncthreads();
  for (int o = 1; o < 512; o <<= 1) {
    int a = (t >= o) ? s[t - o] : 0;
    __syncthreads();
    s[t] += a;
    __syncthreads();
  }
  if (t < NBK) {
    int excl = s[t] - v;
    bstart[t] = excl;
    bcur[t] = excl;
  }
  if (t == 511) bstart[NBK] = s[511];
  if (t == 0) dinv16[N] = __ushort_as_half((unsigned short)0);  // pad sentinel w=0
}

// scatter packed {src:16 | (dst&127)<<16} into bucket regions
__global__ __launch_bounds__(256) void kb_scatter(const int* __restrict__ src,
                                                  const int* __restrict__ dst,
                                                  int* __restrict__ bcur,
                                                  unsigned* __restrict__ tmp,
                                                  int E, int NBK, int chunk) {
  __shared__ int h[MAXBK];
  __shared__ int base[MAXBK];
  int lo = blockIdx.x * chunk;
  int hi = min(lo + chunk, E);
  for (int i = threadIdx.x; i < NBK; i += 256) h[i] = 0;
  __syncthreads();
  for (int e = lo + threadIdx.x; e < hi; e += 256) atomicAdd(&h[dst[e] >> BSH], 1);
  __syncthreads();
  for (int i = threadIdx.x; i < NBK; i += 256) {
    int c = h[i];
    base[i] = c ? atomicAdd(&bcur[i], c) : 0;
    h[i] = 0;
  }
  __syncthreads();
  for (int e = lo + threadIdx.x; e < hi; e += 256) {
    int d = dst[e];
    int b = d >> BSH;
    int p = base[b] + atomicAdd(&h[b], 1);
    tmp[p] = (unsigned)src[e] | ((unsigned)(d & (BNODES - 1)) << 16);
  }
}

// ---- merged build: per-bucket count -> pad-scan -> cursor-reserve -> rs/dinv
// -> final scatter of ushort src into padded CSR (pad sentinel = N).
__global__ __launch_bounds__(256) void kb_build(const unsigned* __restrict__ tmp,
                                                const int* __restrict__ bstart,
                                                int* __restrict__ cursor,
                                                float* __restrict__ dinv,
                                                __half* __restrict__ dinv16,
                                                int2* __restrict__ rs,
                                                unsigned short* __restrict__ ew,
                                                int N) {
  __shared__ int hcnt[BNODES];
  __shared__ int scn[BNODES];
  __shared__ int beg[BNODES];
  __shared__ int lcur[BNODES];
  __shared__ int gbs;
  int b = blockIdx.x;
  int t = threadIdx.x;
  for (int i = t; i < BNODES; i += 256) hcnt[i] = 0;
  __syncthreads();
  int lo = bstart[b], hi = bstart[b + 1];
  for (int p = lo + t; p < hi; p += 256)
    atomicAdd(&hcnt[(tmp[p] >> 16) & (BNODES - 1)], 1);
  __syncthreads();
  int pcnt = 0;
  if (t < BNODES) {
    pcnt = (hcnt[t] + 3) & ~3;
    scn[t] = pcnt;
  }
  __syncthreads();
  for (int o = 1; o < BNODES; o <<= 1) {
    int a = (t < BNODES && t >= o) ? scn[t - o] : 0;
    __syncthreads();
    if (t < BNODES) scn[t] += a;
    __syncthreads();
  }
  if (t == 0) gbs = atomicAdd(cursor, scn[BNODES - 1]);
  __syncthreads();
  if (t < BNODES) {
    int v = (b << BSH) + t;
    int bg = gbs + scn[t] - pcnt;
    beg[t] = bg;
    lcur[t] = 0;
    if (v < N) {
      rs[v] = make_int2(bg, bg + pcnt);
      float di = rsqrtf((float)hcnt[t] + 1.0f);  // +1 self-loop
      dinv[v] = di;
      dinv16[v] = __float2half(di);
    }
  }
  __syncthreads();
  for (int p = lo + t; p < hi; p += 256) {
    unsigned u = tmp[p];
    int dl = (u >> 16) & (BNODES - 1);
    int pos = beg[dl] + atomicAdd(&lcur[dl], 1);
    ew[pos] = (unsigned short)(u & 0xFFFF);
  }
  __syncthreads();
  if (t < BNODES) {
    int p = beg[t] + lcur[t];
    int end = beg[t] + ((hcnt[t] + 3) & ~3);
    for (; p < end; ++p) ew[p] = (unsigned short)N;  // sentinel: dinv16[N]=0
  }
}

// ---- fused: agg96 (bias+relu) -> tiny LDS -> MFMA with pre-transposed W -----
// 16 nodes per block: 4 waves x 4 sequential nodes. ew = ushort src; weight
// looked up from dinv16 (L2-hot 100KB table, wave-uniform loads).
template <int DOUT>
__global__ __launch_bounds__(256) void kfuse(const __half* __restrict__ t,
                                             const int2* __restrict__ rs,
                                             const unsigned short* __restrict__ ew,
                                             const float* __restrict__ dinv,
                                             const __half* __restrict__ dinv16,
                                             const float* __restrict__ bias,
                                             const _Float16* __restrict__ Wt,
                                             __half* __restrict__ out, int N) {
  __shared__ _Float16 A[16 * 104];
  const int tid = threadIdx.x;
  const int wave = tid >> 6;
  const int lane = tid & 63;
  const int li = (lane < 48) ? lane : 47;
  const int fb = li << 2;
  const char* tb = (const char*)t;
  const float bx = bias[2 * li];
  const float by = bias[2 * li + 1];
#pragma unroll
  for (int i = 0; i < 4; ++i) {
    int row = wave * 4 + i;
    int v = blockIdx.x * 16 + row;
    if (v < N) {
      float dv = dinv[v];
      float2 acc;
      {
        __half2 r = *(const __half2*)(tb + (size_t)v * 192 + fb);
        float2 f = __half22float2(r);
        acc.x = dv * f.x;
        acc.y = dv * f.y;
      }
      int2 range = rs[v];
      int e = range.x;
      const int e1 = range.y;              // padded to x4, 8B aligned
      for (; e < e1; e += 4) {
        ushort4 q = *(const ushort4*)(ew + e);  // 4 edges, wave-uniform
        __half2 r0 = *(const __half2*)(tb + (size_t)q.x * 192 + fb);
        __half2 r1 = *(const __half2*)(tb + (size_t)q.y * 192 + fb);
        __half2 r2 = *(const __half2*)(tb + (size_t)q.z * 192 + fb);
        __half2 r3 = *(const __half2*)(tb + (size_t)q.w * 192 + fb);
        float w0 = __half2float(dinv16[q.x]);
        float w1 = __half2float(dinv16[q.y]);
        float w2 = __half2float(dinv16[q.z]);
        float w3 = __half2float(dinv16[q.w]);
        float2 a0 = __half22float2(r0), a1 = __half22float2(r1);
        float2 a2 = __half22float2(r2), a3 = __half22float2(r3);
        acc.x = fmaf(w0, a0.x, acc.x); acc.y = fmaf(w0, a0.y, acc.y);
        acc.x = fmaf(w1, a1.x, acc.x); acc.y = fmaf(w1, a1.y, acc.y);
        acc.x = fmaf(w2, a2.x, acc.x); acc.y = fmaf(w2, a2.y, acc.y);
        acc.x = fmaf(w3, a3.x, acc.x); acc.y = fmaf(w3, a3.y, acc.y);
      }
      if (lane < 48) {
        float rx = fmaxf(fmaf(dv, acc.x, bx), 0.f);
        float ry = fmaxf(fmaf(dv, acc.y, by), 0.f);
        A[row * 104 + 2 * li] = (_Float16)rx;
        A[row * 104 + 2 * li + 1] = (_Float16)ry;
      }
    }
  }
  __syncthreads();
  const int crow = lane & 15;
  const int kgrp = lane >> 4;
  f16x8 a[3];
  const _Float16* arow = &A[crow * 104 + kgrp * 8];
#pragma unroll
  for (int ks = 0; ks < 3; ++ks) a[ks] = *(const f16x8*)(arow + ks * 32);
  const int rbase = blockIdx.x * 16 + kgrp * 4;
#pragma unroll
  for (int w2 = 0; w2 < 2; ++w2) {
    int nt = wave + 4 * w2;
    if (nt >= DOUT / 16) break;
    f32x4 c = {0.f, 0.f, 0.f, 0.f};
#pragma unroll
    for (int ks = 0; ks < 3; ++ks) {
      f16x8 b = *(const f16x8*)&Wt[(nt * 16 + crow) * 96 + ks * 32 + kgrp * 8];
      c = __builtin_amdgcn_mfma_f32_16x16x32_f16(a[ks], b, c, 0, 0, 0);
    }
#pragma unroll
    for (int reg = 0; reg < 4; ++reg) {
      int R = rbase + reg;
      if (R < N) out[(size_t)R * DOUT + nt * 16 + crow] = (__half)c[reg];
    }
  }
}

// D=32 final layer: half-wave per node, f32 out
__global__ __launch_bounds__(256) void k_agg32h(const __half* __restrict__ t,
                                                const int2* __restrict__ rs,
                                                const unsigned short* __restrict__ ew,
                                                const float* __restrict__ dinv,
                                                const __half* __restrict__ dinv16,
                                                const float* __restrict__ bias,
                                                float* __restrict__ out, int N) {
  int half = threadIdx.x >> 5;
  int lane = threadIdx.x & 31;
  int v = blockIdx.x * 8 + half;
  if (v >= N) return;
  const char* tb = (const char*)t;
  const int fb = lane << 1;
  float dv = dinv[v];
  float acc = dv * __half2float(*(const __half*)(tb + (size_t)v * 64 + fb));
  int2 range = rs[v];
  int e = range.x;
  const int e1 = range.y;
  for (; e < e1; e += 4) {
    ushort4 q = *(const ushort4*)(ew + e);
    float a0 = __half2float(*(const __half*)(tb + (size_t)q.x * 64 + fb));
    float a1 = __half2float(*(const __half*)(tb + (size_t)q.y * 64 + fb));
    float a2 = __half2float(*(const __half*)(tb + (size_t)q.z * 64 + fb));
    float a3 = __half2float(*(const __half*)(tb + (size_t)q.w * 64 + fb));
    acc = fmaf(__half2float(dinv16[q.x]), a0, acc);
    acc = fmaf(__half2float(dinv16[q.y]), a1, acc);
    acc = fmaf(__half2float(dinv16[q.z]), a2, acc);
    acc = fmaf(__half2float(dinv16[q.w]), a3, acc);
  }
  out[(size_t)v * 32 + lane] = fmaf(dv, acc, bias[lane]);
}

// ---- launch ----------------------------------------------------------------

extern "C" void kernel_launch(void* const* d_in, const int* in_sizes, int n_in,
                              void* d_out, int out_size, void* d_ws, size_t ws_size,
                              hipStream_t stream) {
  const float* x  = (const float*)d_in[0];
  const int*   ei = (const int*)d_in[1];
  const float* W1 = (const float*)d_in[2];
  const float* b1 = (const float*)d_in[3];
  const float* W2 = (const float*)d_in[4];
  const float* b2 = (const float*)d_in[5];
  const float* W3 = (const float*)d_in[6];
  const float* b3 = (const float*)d_in[7];
  float* out = (float*)d_out;

  const int N = in_sizes[0] / KDIM;
  const int E = in_sizes[1] / 2;
  const int* src = ei;
  const int* dst = ei + E;
  const int NBK = (N + BNODES - 1) >> BSH;

  char* w = (char*)d_ws;
  size_t off = 0;
  auto alloc = [&](size_t bytes) {
    char* p = w + off;
    off = (off + bytes + 255) & ~(size_t)255;
    return p;
  };
  int*            gbcnt  = (int*)alloc((size_t)(MAXBK + 8) * 4);  // +cursor
  int*            bstart = (int*)alloc((size_t)(MAXBK + 1) * 4);
  int*            bcur   = (int*)alloc((size_t)MAXBK * 4);
  float*          dinv   = (float*)alloc((size_t)N * 4);
  __half*         dinv16 = (__half*)alloc((size_t)(N + 1) * 2);
  int2*           rs     = (int2*)alloc((size_t)N * 8);
  unsigned*       tmp    = (unsigned*)alloc((size_t)E * 4);
  unsigned short* ew     = (unsigned short*)alloc((size_t)(E + 4 * (size_t)N + 16) * 2);
  __half*         tA     = (__half*)alloc((size_t)(N + 1) * KDIM * 2);  // +sentinel row
  __half*         tB     = (__half*)alloc((size_t)(N + 1) * KDIM * 2);
  __half*         tC     = (__half*)alloc((size_t)(N + 1) * 32 * 2);
  _Float16*       Wt2    = (_Float16*)alloc((size_t)96 * 96 * 2);
  _Float16*       Wt3    = (_Float16*)alloc((size_t)32 * 96 * 2);
  int*            cursor = gbcnt + MAXBK;

  hipMemsetAsync(gbcnt, 0, (size_t)(MAXBK + 8) * 4, stream);

  const int NCH = 512;
  const int chunk = (E + NCH - 1) / NCH;
  const int gG = (N + 63) / 64;
  const int gF = (N + 15) / 16;
  const int gA8 = (N + 7) / 8;

  khist_gemm1<<<256 + gG + 1, 256, 0, stream>>>(dst, gbcnt, E, NBK, x, W1, tA, N,
                                                W2, W3, Wt2, Wt3, gG);
  kb_scanb<<<1, 512, 0, stream>>>(gbcnt, bstart, bcur, NBK, dinv16, N);
  kb_scatter<<<NCH, 256, 0, stream>>>(src, dst, bcur, tmp, E, NBK, chunk);
  kb_build<<<NBK, 256, 0, stream>>>(tmp, bstart, cursor, dinv, dinv16, rs, ew, N);

  kfuse<96><<<gF, 256, 0, stream>>>(tA, rs, ew, dinv, dinv16, b1, Wt2, tB, N);
  kfuse<32><<<gF, 256, 0, stream>>>(tB, rs, ew, dinv, dinv16, b2, Wt3, tC, N);
  k_agg32h<<<gA8, 256, 0, stream>>>(tC, rs, ew, dinv, dinv16, b3, out, N);
}

// Round 15
// 141.412 us; speedup vs baseline: 1.2661x; 1.1456x over previous
//
#include <hip/hip_runtime.h>
#include <hip/hip_bf16.h>
#include <hip/hip_fp16.h>

static constexpr int KDIM = 96;
static constexpr int BSH = 7;              // 128 nodes per bucket
static constexpr int BNODES = 1 << BSH;
static constexpr int MAXBK = 400;          // >= ceil(50000/128)=391

typedef _Float16 f16x8 __attribute__((ext_vector_type(8)));
typedef float f32x4 __attribute__((ext_vector_type(4)));

// ---- GEMM96 body (f32 A, fp16 out), W transposed in LDS --------------------
__device__ __forceinline__ void gemm96_f32_body(const float* __restrict__ x,
                                                const float* __restrict__ Wg,
                                                __half* __restrict__ out, int N,
                                                int gb, char* sm) {
  _Float16* Wt = (_Float16*)sm;            // [96][104]
  const int tid = threadIdx.x;
  for (int i = tid; i < 96 * 96; i += 256) {
    int k = i / 96, j = i - k * 96;
    Wt[j * 104 + k] = (_Float16)Wg[i];
  }
  __syncthreads();
  const int wave = tid >> 6;
  const int l = tid & 63;
  const int crow = l & 15;
  const int kgrp = l >> 4;
  int r = gb * 64 + wave * 16 + crow;
  int rc = (r < N) ? r : (N - 1);
  f16x8 a[3];
  const float* ap = x + (size_t)rc * 96 + kgrp * 8;
#pragma unroll
  for (int ks = 0; ks < 3; ++ks) {
    float4 u = *(const float4*)(ap + ks * 32);
    float4 w = *(const float4*)(ap + ks * 32 + 4);
    a[ks][0] = (_Float16)u.x; a[ks][1] = (_Float16)u.y;
    a[ks][2] = (_Float16)u.z; a[ks][3] = (_Float16)u.w;
    a[ks][4] = (_Float16)w.x; a[ks][5] = (_Float16)w.y;
    a[ks][6] = (_Float16)w.z; a[ks][7] = (_Float16)w.w;
  }
  const int rbase = gb * 64 + wave * 16 + kgrp * 4;
#pragma unroll
  for (int nt = 0; nt < 6; ++nt) {
    f32x4 c = {0.f, 0.f, 0.f, 0.f};
#pragma unroll
    for (int ks = 0; ks < 3; ++ks) {
      f16x8 b = *(const f16x8*)&Wt[(nt * 16 + crow) * 104 + ks * 32 + kgrp * 8];
      c = __builtin_amdgcn_mfma_f32_16x16x32_f16(a[ks], b, c, 0, 0, 0);
    }
#pragma unroll
    for (int reg = 0; reg < 4; ++reg) {
      int R = rbase + reg;
      if (R < N) out[(size_t)R * 96 + nt * 16 + crow] = (__half)c[reg];
    }
  }
}

// ---- fat kernel: hist (blocks<256) + GEMM1 (next gG) + W-transpose (last) --
__global__ __launch_bounds__(256) void khist_gemm1(const int* __restrict__ dst,
                                                   int* __restrict__ gbcnt,
                                                   int E, int NBK,
                                                   const float* __restrict__ x,
                                                   const float* __restrict__ W1,
                                                   __half* __restrict__ tA, int N,
                                                   const float* __restrict__ W2,
                                                   const float* __restrict__ W3,
                                                   _Float16* __restrict__ Wt2,
                                                   _Float16* __restrict__ Wt3,
                                                   int gG) {
  __shared__ __align__(16) char sm[96 * 104 * 2];
  if (blockIdx.x < 256) {
    int* h = (int*)sm;
    for (int i = threadIdx.x; i < NBK; i += 256) h[i] = 0;
    __syncthreads();
    for (int e = blockIdx.x * 256 + threadIdx.x; e < E; e += 256 * 256)
      atomicAdd(&h[dst[e] >> BSH], 1);
    __syncthreads();
    for (int i = threadIdx.x; i < NBK; i += 256)
      if (h[i]) atomicAdd(&gbcnt[i], h[i]);
  } else if (blockIdx.x < 256 + gG) {
    gemm96_f32_body(x, W1, tA, N, blockIdx.x - 256, sm);
  } else {
    for (int i = threadIdx.x; i < 96 * 96; i += 256) {
      int k = i / 96, j = i - k * 96;
      Wt2[j * 96 + k] = (_Float16)W2[i];
    }
    for (int i = threadIdx.x; i < 96 * 32; i += 256) {
      int k = i / 32, j = i - k * 32;
      Wt3[j * 96 + k] = (_Float16)W3[i];
    }
  }
}

__global__ void kb_scanb(const int* __restrict__ gbcnt, int* __restrict__ bstart,
                         int* __restrict__ bcur, int NBK,
                         __half* __restrict__ dinv16, int N) {
  __shared__ int s[512];
  int t = threadIdx.x;
  int v = (t < NBK) ? gbcnt[t] : 0;
  s[t] = v;
  __syncthreads();
  for (int o = 1; o < 512; o <<= 1) {
    int a = (t >= o) ? s[t - o] : 0;
    __syncthreads();
    s[t] += a;
    __syncthreads();
  }
  if (t < NBK) {
    int excl = s[t] - v;
    bstart[t] = excl;
    bcur[t] = excl;
  }
  if (t == 511) bstart[NBK] = s[511];
  if (t == 0) dinv16[N] = __ushort_as_half((unsigned short)0);  // pad sentinel w=0
}

// scatter packed {src:16 | (dst&127)<<16} into bucket regions
__global__ __launch_bounds__(256) void kb_scatter(const int* __restrict__ src,
                                                  const int* __restrict__ dst,
                                                  int* __restrict__ bcur,
                                                  unsigned* __restrict__ tmp,
                                                  int E, int NBK, int chunk) {
  __shared__ int h[MAXBK];
  __shared__ int base[MAXBK];
  int lo = blockIdx.x * chunk;
  int hi = min(lo + chunk, E);
  for (int i = threadIdx.x; i < NBK; i += 256) h[i] = 0;
  __syncthreads();
  for (int e = lo + threadIdx.x; e < hi; e += 256) atomicAdd(&h[dst[e] >> BSH], 1);
  __syncthreads();
  for (int i = threadIdx.x; i < NBK; i += 256) {
    int c = h[i];
    base[i] = c ? atomicAdd(&bcur[i], c) : 0;
    h[i] = 0;
  }
  __syncthreads();
  for (int e = lo + threadIdx.x; e < hi; e += 256) {
    int d = dst[e];
    int b = d >> BSH;
    int p = base[b] + atomicAdd(&h[b], 1);
    tmp[p] = (unsigned)src[e] | ((unsigned)(d & (BNODES - 1)) << 16);
  }
}

// ---- merged build: per-bucket count -> pad-scan -> cursor-reserve -> rs/dinv
// -> final scatter of ushort src into padded CSR (pad sentinel = N).
__global__ __launch_bounds__(256) void kb_build(const unsigned* __restrict__ tmp,
                                                const int* __restrict__ bstart,
                                                int* __restrict__ cursor,
                                                float* __restrict__ dinv,
                                                __half* __restrict__ dinv16,
                                                int2* __restrict__ rs,
                                                unsigned short* __restrict__ ew,
                                                int N) {
  __shared__ int hcnt[BNODES];
  __shared__ int scn[BNODES];
  __shared__ int beg[BNODES];
  __shared__ int lcur[BNODES];
  __shared__ int gbs;
  int b = blockIdx.x;
  int t = threadIdx.x;
  for (int i = t; i < BNODES; i += 256) hcnt[i] = 0;
  __syncthreads();
  int lo = bstart[b], hi = bstart[b + 1];
  for (int p = lo + t; p < hi; p += 256)
    atomicAdd(&hcnt[(tmp[p] >> 16) & (BNODES - 1)], 1);
  __syncthreads();
  int pcnt = 0;
  if (t < BNODES) {
    pcnt = (hcnt[t] + 3) & ~3;
    scn[t] = pcnt;
  }
  __syncthreads();
  for (int o = 1; o < BNODES; o <<= 1) {
    int a = (t < BNODES && t >= o) ? scn[t - o] : 0;
    __syncthreads();
    if (t < BNODES) scn[t] += a;
    __syncthreads();
  }
  if (t == 0) gbs = atomicAdd(cursor, scn[BNODES - 1]);
  __syncthreads();
  if (t < BNODES) {
    int v = (b << BSH) + t;
    int bg = gbs + scn[t] - pcnt;
    beg[t] = bg;
    lcur[t] = 0;
    if (v < N) {
      rs[v] = make_int2(bg, bg + pcnt);
      float di = rsqrtf((float)hcnt[t] + 1.0f);  // +1 self-loop
      dinv[v] = di;
      dinv16[v] = __float2half(di);
    }
  }
  __syncthreads();
  for (int p = lo + t; p < hi; p += 256) {
    unsigned u = tmp[p];
    int dl = (u >> 16) & (BNODES - 1);
    int pos = beg[dl] + atomicAdd(&lcur[dl], 1);
    ew[pos] = (unsigned short)(u & 0xFFFF);
  }
  __syncthreads();
  if (t < BNODES) {
    int p = beg[t] + lcur[t];
    int end = beg[t] + ((hcnt[t] + 3) & ~3);
    for (; p < end; ++p) ew[p] = (unsigned short)N;  // sentinel: dinv16[N]=0
  }
}

// ---- fused: agg96 (bias+relu) -> tiny LDS -> MFMA with pre-transposed W -----
// 16 nodes per block: 4 waves x 4 sequential nodes. 8-deep gather unroll:
// 8 independent row-loads in flight per lane (latency x concurrency bound).
template <int DOUT>
__global__ __launch_bounds__(256) void kfuse(const __half* __restrict__ t,
                                             const int2* __restrict__ rs,
                                             const unsigned short* __restrict__ ew,
                                             const float* __restrict__ dinv,
                                             const __half* __restrict__ dinv16,
                                             const float* __restrict__ bias,
                                             const _Float16* __restrict__ Wt,
                                             __half* __restrict__ out, int N) {
  __shared__ _Float16 A[16 * 104];
  const int tid = threadIdx.x;
  const int wave = tid >> 6;
  const int lane = tid & 63;
  const int li = (lane < 48) ? lane : 47;
  const int fb = li << 2;
  const char* tb = (const char*)t;
  const float bx = bias[2 * li];
  const float by = bias[2 * li + 1];
#pragma unroll
  for (int i = 0; i < 4; ++i) {
    int row = wave * 4 + i;
    int v = blockIdx.x * 16 + row;
    if (v < N) {
      float dv = dinv[v];
      float2 acc;
      {
        __half2 r = *(const __half2*)(tb + (size_t)v * 192 + fb);
        float2 f = __half22float2(r);
        acc.x = dv * f.x;
        acc.y = dv * f.y;
      }
      int2 range = rs[v];
      int e = range.x;
      const int e1 = range.y;              // padded to x4
      for (; e + 8 <= e1; e += 8) {        // 8 independent gather chains
        ushort4 qa = *(const ushort4*)(ew + e);
        ushort4 qb = *(const ushort4*)(ew + e + 4);
        __half2 r0 = *(const __half2*)(tb + (size_t)qa.x * 192 + fb);
        __half2 r1 = *(const __half2*)(tb + (size_t)qa.y * 192 + fb);
        __half2 r2 = *(const __half2*)(tb + (size_t)qa.z * 192 + fb);
        __half2 r3 = *(const __half2*)(tb + (size_t)qa.w * 192 + fb);
        __half2 r4 = *(const __half2*)(tb + (size_t)qb.x * 192 + fb);
        __half2 r5 = *(const __half2*)(tb + (size_t)qb.y * 192 + fb);
        __half2 r6 = *(const __half2*)(tb + (size_t)qb.z * 192 + fb);
        __half2 r7 = *(const __half2*)(tb + (size_t)qb.w * 192 + fb);
        float w0 = __half2float(dinv16[qa.x]);
        float w1 = __half2float(dinv16[qa.y]);
        float w2 = __half2float(dinv16[qa.z]);
        float w3 = __half2float(dinv16[qa.w]);
        float w4 = __half2float(dinv16[qb.x]);
        float w5 = __half2float(dinv16[qb.y]);
        float w6 = __half2float(dinv16[qb.z]);
        float w7 = __half2float(dinv16[qb.w]);
        float2 a0 = __half22float2(r0), a1 = __half22float2(r1);
        float2 a2 = __half22float2(r2), a3 = __half22float2(r3);
        float2 a4 = __half22float2(r4), a5 = __half22float2(r5);
        float2 a6 = __half22float2(r6), a7 = __half22float2(r7);
        acc.x = fmaf(w0, a0.x, acc.x); acc.y = fmaf(w0, a0.y, acc.y);
        acc.x = fmaf(w1, a1.x, acc.x); acc.y = fmaf(w1, a1.y, acc.y);
        acc.x = fmaf(w2, a2.x, acc.x); acc.y = fmaf(w2, a2.y, acc.y);
        acc.x = fmaf(w3, a3.x, acc.x); acc.y = fmaf(w3, a3.y, acc.y);
        acc.x = fmaf(w4, a4.x, acc.x); acc.y = fmaf(w4, a4.y, acc.y);
        acc.x = fmaf(w5, a5.x, acc.x); acc.y = fmaf(w5, a5.y, acc.y);
        acc.x = fmaf(w6, a6.x, acc.x); acc.y = fmaf(w6, a6.y, acc.y);
        acc.x = fmaf(w7, a7.x, acc.x); acc.y = fmaf(w7, a7.y, acc.y);
      }
      if (e < e1) {                        // remainder: exactly 4
        ushort4 q = *(const ushort4*)(ew + e);
        __half2 r0 = *(const __half2*)(tb + (size_t)q.x * 192 + fb);
        __half2 r1 = *(const __half2*)(tb + (size_t)q.y * 192 + fb);
        __half2 r2 = *(const __half2*)(tb + (size_t)q.z * 192 + fb);
        __half2 r3 = *(const __half2*)(tb + (size_t)q.w * 192 + fb);
        float w0 = __half2float(dinv16[q.x]);
        float w1 = __half2float(dinv16[q.y]);
        float w2 = __half2float(dinv16[q.z]);
        float w3 = __half2float(dinv16[q.w]);
        float2 a0 = __half22float2(r0), a1 = __half22float2(r1);
        float2 a2 = __half22float2(r2), a3 = __half22float2(r3);
        acc.x = fmaf(w0, a0.x, acc.x); acc.y = fmaf(w0, a0.y, acc.y);
        acc.x = fmaf(w1, a1.x, acc.x); acc.y = fmaf(w1, a1.y, acc.y);
        acc.x = fmaf(w2, a2.x, acc.x); acc.y = fmaf(w2, a2.y, acc.y);
        acc.x = fmaf(w3, a3.x, acc.x); acc.y = fmaf(w3, a3.y, acc.y);
      }
      if (lane < 48) {
        float rx = fmaxf(fmaf(dv, acc.x, bx), 0.f);
        float ry = fmaxf(fmaf(dv, acc.y, by), 0.f);
        A[row * 104 + 2 * li] = (_Float16)rx;
        A[row * 104 + 2 * li + 1] = (_Float16)ry;
      }
    }
  }
  __syncthreads();
  const int crow = lane & 15;
  const int kgrp = lane >> 4;
  f16x8 a[3];
  const _Float16* arow = &A[crow * 104 + kgrp * 8];
#pragma unroll
  for (int ks = 0; ks < 3; ++ks) a[ks] = *(const f16x8*)(arow + ks * 32);
  const int rbase = blockIdx.x * 16 + kgrp * 4;
#pragma unroll
  for (int w2 = 0; w2 < 2; ++w2) {
    int nt = wave + 4 * w2;
    if (nt >= DOUT / 16) break;
    f32x4 c = {0.f, 0.f, 0.f, 0.f};
#pragma unroll
    for (int ks = 0; ks < 3; ++ks) {
      f16x8 b = *(const f16x8*)&Wt[(nt * 16 + crow) * 96 + ks * 32 + kgrp * 8];
      c = __builtin_amdgcn_mfma_f32_16x16x32_f16(a[ks], b, c, 0, 0, 0);
    }
#pragma unroll
    for (int reg = 0; reg < 4; ++reg) {
      int R = rbase + reg;
      if (R < N) out[(size_t)R * DOUT + nt * 16 + crow] = (__half)c[reg];
    }
  }
}

// D=32 final layer: half-wave per node, f32 out, 8-deep gather unroll
__global__ __launch_bounds__(256) void k_agg32h(const __half* __restrict__ t,
                                                const int2* __restrict__ rs,
                                                const unsigned short* __restrict__ ew,
                                                const float* __restrict__ dinv,
                                                const __half* __restrict__ dinv16,
                                                const float* __restrict__ bias,
                                                float* __restrict__ out, int N) {
  int half = threadIdx.x >> 5;
  int lane = threadIdx.x & 31;
  int v = blockIdx.x * 8 + half;
  if (v >= N) return;
  const char* tb = (const char*)t;
  const int fb = lane << 1;
  float dv = dinv[v];
  float acc = dv * __half2float(*(const __half*)(tb + (size_t)v * 64 + fb));
  int2 range = rs[v];
  int e = range.x;
  const int e1 = range.y;
  for (; e + 8 <= e1; e += 8) {
    ushort4 qa = *(const ushort4*)(ew + e);
    ushort4 qb = *(const ushort4*)(ew + e + 4);
    float a0 = __half2float(*(const __half*)(tb + (size_t)qa.x * 64 + fb));
    float a1 = __half2float(*(const __half*)(tb + (size_t)qa.y * 64 + fb));
    float a2 = __half2float(*(const __half*)(tb + (size_t)qa.z * 64 + fb));
    float a3 = __half2float(*(const __half*)(tb + (size_t)qa.w * 64 + fb));
    float a4 = __half2float(*(const __half*)(tb + (size_t)qb.x * 64 + fb));
    float a5 = __half2float(*(const __half*)(tb + (size_t)qb.y * 64 + fb));
    float a6 = __half2float(*(const __half*)(tb + (size_t)qb.z * 64 + fb));
    float a7 = __half2float(*(const __half*)(tb + (size_t)qb.w * 64 + fb));
    acc = fmaf(__half2float(dinv16[qa.x]), a0, acc);
    acc = fmaf(__half2float(dinv16[qa.y]), a1, acc);
    acc = fmaf(__half2float(dinv16[qa.z]), a2, acc);
    acc = fmaf(__half2float(dinv16[qa.w]), a3, acc);
    acc = fmaf(__half2float(dinv16[qb.x]), a4, acc);
    acc = fmaf(__half2float(dinv16[qb.y]), a5, acc);
    acc = fmaf(__half2float(dinv16[qb.z]), a6, acc);
    acc = fmaf(__half2float(dinv16[qb.w]), a7, acc);
  }
  if (e < e1) {
    ushort4 q = *(const ushort4*)(ew + e);
    float a0 = __half2float(*(const __half*)(tb + (size_t)q.x * 64 + fb));
    float a1 = __half2float(*(const __half*)(tb + (size_t)q.y * 64 + fb));
    float a2 = __half2float(*(const __half*)(tb + (size_t)q.z * 64 + fb));
    float a3 = __half2float(*(const __half*)(tb + (size_t)q.w * 64 + fb));
    acc = fmaf(__half2float(dinv16[q.x]), a0, acc);
    acc = fmaf(__half2float(dinv16[q.y]), a1, acc);
    acc = fmaf(__half2float(dinv16[q.z]), a2, acc);
    acc = fmaf(__half2float(dinv16[q.w]), a3, acc);
  }
  out[(size_t)v * 32 + lane] = fmaf(dv, acc, bias[lane]);
}

// ---- launch ----------------------------------------------------------------

extern "C" void kernel_launch(void* const* d_in, const int* in_sizes, int n_in,
                              void* d_out, int out_size, void* d_ws, size_t ws_size,
                              hipStream_t stream) {
  const float* x  = (const float*)d_in[0];
  const int*   ei = (const int*)d_in[1];
  const float* W1 = (const float*)d_in[2];
  const float* b1 = (const float*)d_in[3];
  const float* W2 = (const float*)d_in[4];
  const float* b2 = (const float*)d_in[5];
  const float* W3 = (const float*)d_in[6];
  const float* b3 = (const float*)d_in[7];
  float* out = (float*)d_out;

  const int N = in_sizes[0] / KDIM;
  const int E = in_sizes[1] / 2;
  const int* src = ei;
  const int* dst = ei + E;
  const int NBK = (N + BNODES - 1) >> BSH;

  char* w = (char*)d_ws;
  size_t off = 0;
  auto alloc = [&](size_t bytes) {
    char* p = w + off;
    off = (off + bytes + 255) & ~(size_t)255;
    return p;
  };
  int*            gbcnt  = (int*)alloc((size_t)(MAXBK + 8) * 4);  // +cursor
  int*            bstart = (int*)alloc((size_t)(MAXBK + 1) * 4);
  int*            bcur   = (int*)alloc((size_t)MAXBK * 4);
  float*          dinv   = (float*)alloc((size_t)N * 4);
  __half*         dinv16 = (__half*)alloc((size_t)(N + 1) * 2);
  int2*           rs     = (int2*)alloc((size_t)N * 8);
  unsigned*       tmp    = (unsigned*)alloc((size_t)E * 4);
  unsigned short* ew     = (unsigned short*)alloc((size_t)(E + 4 * (size_t)N + 16) * 2);
  __half*         tA     = (__half*)alloc((size_t)(N + 1) * KDIM * 2);  // +sentinel row
  __half*         tB     = (__half*)alloc((size_t)(N + 1) * KDIM * 2);
  __half*         tC     = (__half*)alloc((size_t)(N + 1) * 32 * 2);
  _Float16*       Wt2    = (_Float16*)alloc((size_t)96 * 96 * 2);
  _Float16*       Wt3    = (_Float16*)alloc((size_t)32 * 96 * 2);
  int*            cursor = gbcnt + MAXBK;

  hipMemsetAsync(gbcnt, 0, (size_t)(MAXBK + 8) * 4, stream);

  const int NCH = 512;
  const int chunk = (E + NCH - 1) / NCH;
  const int gG = (N + 63) / 64;
  const int gF = (N + 15) / 16;
  const int gA8 = (N + 7) / 8;

  khist_gemm1<<<256 + gG + 1, 256, 0, stream>>>(dst, gbcnt, E, NBK, x, W1, tA, N,
                                                W2, W3, Wt2, Wt3, gG);
  kb_scanb<<<1, 512, 0, stream>>>(gbcnt, bstart, bcur, NBK, dinv16, N);
  kb_scatter<<<NCH, 256, 0, stream>>>(src, dst, bcur, tmp, E, NBK, chunk);
  kb_build<<<NBK, 256, 0, stream>>>(tmp, bstart, cursor, dinv, dinv16, rs, ew, N);

  kfuse<96><<<gF, 256, 0, stream>>>(tA, rs, ew, dinv, dinv16, b1, Wt2, tB, N);
  kfuse<32><<<gF, 256, 0, stream>>>(tB, rs, ew, dinv, dinv16, b2, Wt3, tC, N);
  k_agg32h<<<gA8, 256, 0, stream>>>(tC, rs, ew, dinv, dinv16, b3, out, N);
}